// Round 7
// baseline (579.396 us; speedup 1.0000x reference)
//
#include <hip/hip_runtime.h>

// GeniePathLayer: GATConv(heads=1,self-loops) -> tanh -> 1-step LSTM
// N=10000, E=320000, D=256. f32 I/O, bf16 MFMA internally.
// 2-launch structure: k_pre (weights + w_s/w_d + zeroing) -> k_mega
// (rows | gemm+edges | gather | lstm, separated by device-scope grid barriers).

#define DIM 256
#define MPAD 10112  // 79 * 128
#define CAP 96      // CSR row capacity; in-deg ~Poisson(32), P(>=96) negligible
#define NB 1024     // mega grid: 4 blocks/CU x 256 CU, exactly co-resident

typedef __attribute__((ext_vector_type(8))) short bf16x8;
typedef __attribute__((ext_vector_type(4))) short s16x4;
typedef __attribute__((ext_vector_type(4))) float f32x4;
typedef __attribute__((ext_vector_type(4))) int i32x4;

typedef const __attribute__((address_space(1))) unsigned gu32;
typedef __attribute__((address_space(3))) unsigned lu32;

__device__ inline unsigned short f2bf(float f){
  unsigned u = __builtin_bit_cast(unsigned, f);
  unsigned r = u + 0x7FFFu + ((u >> 16) & 1u);
  return (unsigned short)(r >> 16);
}
__device__ inline float bf2f(unsigned short s){
  unsigned u = ((unsigned)s) << 16;
  return __builtin_bit_cast(float, u);
}

// Device-scope arrive-and-wait barrier. bar[idx] zeroed by k_pre each launch.
__device__ inline void gbar(int* bar, int idx, int nb){
  __syncthreads();
  if (threadIdx.x == 0){
    __hip_atomic_fetch_add(bar + idx, 1, __ATOMIC_RELEASE, __HIP_MEMORY_SCOPE_AGENT);
    while (__hip_atomic_load(bar + idx, __ATOMIC_ACQUIRE, __HIP_MEMORY_SCOPE_AGENT) < nb)
      __builtin_amdgcn_s_sleep(8);
  }
  __syncthreads();
}

// Weights + attention-vector precompute + zeroing:
//  bar[0:8]=0; w_s=W_gat@att_src, w_d=W_gat@att_dst; curs=0;
//  WgT[d][k]=bf16(W_gat[k][d]); Wcat[j]=[W_ih[j]|W_hh[j]] bf16.
__global__ __launch_bounds__(256) void k_pre(
    const float* __restrict__ W_gat, const float* __restrict__ W_ih,
    const float* __restrict__ W_hh,  const float* __restrict__ att_s,
    const float* __restrict__ att_d,
    short* __restrict__ WgT, short* __restrict__ Wcat,
    float* __restrict__ w_s, float* __restrict__ w_d,
    int* __restrict__ curs, int* __restrict__ bar, int N){
  long z0 = 8, z1 = 512, z2 = N / 4, z3 = 16384, z4 = 131072;
  long total = z0 + z1 + z2 + z3 + z4;
  for (long i = blockIdx.x * 256L + threadIdx.x; i < total; i += (long)gridDim.x * 256){
    long p = i;
    if (p < z0){ bar[p] = 0; continue; }
    p -= z0;
    if (p < z1){
      int k = (int)(p & 255);
      const float* av = (p < 256) ? att_s : att_d;
      const float* row = W_gat + (long)k * 256;
      float acc = 0.f;
      for (int dd = 0; dd < 256; dd += 4){
        f32x4 wv = *(const f32x4*)(row + dd);
        f32x4 a4 = *(const f32x4*)(av + dd);
        acc += wv[0]*a4[0] + wv[1]*a4[1] + wv[2]*a4[2] + wv[3]*a4[3];
      }
      if (p < 256) w_s[k] = acc; else w_d[k] = acc;
      continue;
    }
    p -= z1;
    if (p < z2){ ((i32x4*)curs)[p] = (i32x4){}; continue; }
    p -= z2;
    if (p < z3){
      long i0 = p * 4;
      int d = (int)(i0 >> 8), k = (int)(i0 & 255);
      s16x4 o;
      #pragma unroll
      for (int j = 0; j < 4; j++) o[j] = (short)f2bf(W_gat[(k + j) * 256 + d]);
      *(s16x4*)(WgT + i0) = o;
      continue;
    }
    p -= z3;
    {
      long i0 = p * 4;
      int jr = (int)(i0 >> 9), k = (int)(i0 & 511);
      f32x4 v = (k < 256) ? *(const f32x4*)(W_ih + (long)jr * 256 + k)
                          : *(const f32x4*)(W_hh + (long)jr * 256 + (k - 256));
      s16x4 o;
      #pragma unroll
      for (int j = 0; j < 4; j++) o[j] = (short)f2bf(v[j]);
      *(s16x4*)(Wcat + i0) = o;
    }
  }
}

// P1 rows -> bar -> P2 (gemm tiles | edge chunks) -> bar -> P3 gather -> bar -> P4 lstm
__global__ __launch_bounds__(256, 4) void k_mega(
    const float* __restrict__ x, const int* __restrict__ ei,
    const float* __restrict__ h, const float* __restrict__ c0,
    const float* __restrict__ b_gat,
    const short* __restrict__ WgT, const short* __restrict__ Wcat,
    const float* __restrict__ w_s, const float* __restrict__ w_d,
    short* __restrict__ x_bf, short* __restrict__ A2, short* __restrict__ xw_bf,
    float* __restrict__ a_s, float* __restrict__ a_d,
    int* curs, int* __restrict__ csr_s, float* __restrict__ csr_e,
    int* bar, float* __restrict__ out, int N, int E){
  __shared__ short lds[16384];  // 32 KB, carved per phase
  int tid = threadIdx.x, wv = tid >> 6, lane = tid & 63;
  int nb = gridDim.x;

  // ---------------- P1: per-row convert + att dots ----------------
  for (int n = blockIdx.x * 4 + wv; n < MPAD; n += nb * 4){
    if (n < N){
      f32x4 xv = *(const f32x4*)(x + (long)n * 256 + lane * 4);
      s16x4 ox;
      #pragma unroll
      for (int j = 0; j < 4; j++) ox[j] = (short)f2bf(xv[j]);
      *(s16x4*)(x_bf + (long)n * 256 + lane * 4) = ox;
      f32x4 ws4 = ((const f32x4*)w_s)[lane];
      f32x4 wd4 = ((const f32x4*)w_d)[lane];
      float ps = xv[0]*ws4[0] + xv[1]*ws4[1] + xv[2]*ws4[2] + xv[3]*ws4[3];
      float pd = xv[0]*wd4[0] + xv[1]*wd4[1] + xv[2]*wd4[2] + xv[3]*wd4[3];
      #pragma unroll
      for (int off = 32; off > 0; off >>= 1){
        ps += __shfl_xor(ps, off);
        pd += __shfl_xor(pd, off);
      }
      if (lane == 0){ a_s[n] = ps; a_d[n] = pd; }
      f32x4 hv = *(const f32x4*)(h + (long)n * 256 + lane * 4);
      s16x4 oh;
      #pragma unroll
      for (int j = 0; j < 4; j++) oh[j] = (short)f2bf(hv[j]);
      *(s16x4*)(A2 + (long)n * 512 + 256 + lane * 4) = oh;
    } else {
      s16x4 z = {};
      *(s16x4*)(x_bf + (long)n * 256 + lane * 4) = z;
      *(s16x4*)(A2 + (long)n * 512 + lane * 4) = z;
      *(s16x4*)(A2 + (long)n * 512 + 256 + lane * 4) = z;
    }
  }
  gbar(bar, 0, nb);

  // ---------------- P2: gemm_xw tiles (316) + edge chunks ----------------
  int nchunks = (E + N + 255) / 256;
  for (int vb = blockIdx.x; vb < 316 + nchunks; vb += nb){
    if (vb < 316){
      int bi = vb % 79, bj = vb / 79;
      short* Al = lds;          // 128x64
      short* Bl = lds + 8192;   // 64x64
      int r = lane & 15, g = lane >> 4;
      f32x4 acc[2][4] = {};
      for (int kt = 0; kt < 256; kt += 64){
        #pragma unroll
        for (int jj = 0; jj < 4; jj++){
          int chunk = jj * 256 + wv * 64 + lane;
          int row = chunk >> 3, cc = chunk & 7;
          int ccs = cc ^ (row & 7);
          const short* gp = x_bf + (long)(bi * 128 + row) * 256 + kt + ccs * 8;
          __builtin_amdgcn_global_load_lds((gu32*)gp, (lu32*)&Al[(jj * 256 + wv * 64) * 8], 16, 0, 0);
        }
        #pragma unroll
        for (int jj = 0; jj < 2; jj++){
          int chunk = jj * 256 + wv * 64 + lane;
          int row = chunk >> 3, cc = chunk & 7;
          int ccs = cc ^ (row & 7);
          const short* gp = WgT + (long)(bj * 64 + row) * 256 + kt + ccs * 8;
          __builtin_amdgcn_global_load_lds((gu32*)gp, (lu32*)&Bl[(jj * 256 + wv * 64) * 8], 16, 0, 0);
        }
        __syncthreads();
        #pragma unroll
        for (int kk = 0; kk < 2; kk++){
          int kx = kk * 64 + g * 16;
          int sw = kx ^ ((r & 7) << 4);
          bf16x8 a0 = *(const bf16x8*)((const char*)Al + (wv * 32 + r) * 128 + sw);
          bf16x8 a1 = *(const bf16x8*)((const char*)Al + (wv * 32 + 16 + r) * 128 + sw);
          #pragma unroll
          for (int t = 0; t < 4; t++){
            bf16x8 b = *(const bf16x8*)((const char*)Bl + (t * 16 + r) * 128 + sw);
            acc[0][t] = __builtin_amdgcn_mfma_f32_16x16x32_bf16(a0, b, acc[0][t], 0, 0, 0);
            acc[1][t] = __builtin_amdgcn_mfma_f32_16x16x32_bf16(a1, b, acc[1][t], 0, 0, 0);
          }
        }
        __syncthreads();
      }
      int row0 = bi * 128 + wv * 32;
      #pragma unroll
      for (int m = 0; m < 2; m++){
        #pragma unroll
        for (int q = 0; q < 4; q++){
          int row = row0 + m * 16 + g * 4 + q;
          if (row < N){
            #pragma unroll
            for (int t = 0; t < 4; t++){
              xw_bf[(long)row * 256 + bj * 64 + t * 16 + r] = (short)f2bf(acc[m][t][q]);
            }
          }
        }
      }
    } else {
      int t = (vb - 316) * 256 + tid;
      if (t < E + N){
        int s = (t < E) ? ei[t] : (t - E);
        int d = (t < E) ? ei[E + t] : (t - E);
        float al = a_s[s] + a_d[d];
        al = (al > 0.f) ? al : 0.2f * al;
        float e = expf(al);
        int pos = atomicAdd(curs + d, 1);
        if (pos < CAP){
          csr_s[d * CAP + pos] = s;
          csr_e[d * CAP + pos] = e;
        }
      }
    }
  }
  gbar(bar, 1, nb);

  // ---------------- P3: gather (8-way ILP) ----------------
  for (int vb = blockIdx.x; vb < (N + 3) / 4; vb += nb){
    int d = vb * 4 + wv;
    if (d < N){
      int cnt = curs[d];
      if (cnt > CAP) cnt = CAP;
      int s0 = d * CAP, s1 = s0 + cnt;
      float esum = 0.f;
      float a0 = 0.f, a1 = 0.f, a2 = 0.f, a3 = 0.f;
      int k = s0;
      for (; k + 7 < s1; k += 8){
        int ss[8]; float ee[8]; s16x4 vvv[8];
        #pragma unroll
        for (int u = 0; u < 8; u++){ ss[u] = csr_s[k + u]; ee[u] = csr_e[k + u]; }
        #pragma unroll
        for (int u = 0; u < 8; u++)
          vvv[u] = *(const s16x4*)(xw_bf + (long)ss[u] * 256 + lane * 4);
        #pragma unroll
        for (int u = 0; u < 8; u++){
          esum += ee[u];
          a0 += ee[u] * bf2f((unsigned short)vvv[u][0]);
          a1 += ee[u] * bf2f((unsigned short)vvv[u][1]);
          a2 += ee[u] * bf2f((unsigned short)vvv[u][2]);
          a3 += ee[u] * bf2f((unsigned short)vvv[u][3]);
        }
      }
      for (; k < s1; k++){
        int s = csr_s[k];
        float e = csr_e[k];
        s16x4 v = *(const s16x4*)(xw_bf + (long)s * 256 + lane * 4);
        esum += e;
        a0 += e * bf2f((unsigned short)v[0]);
        a1 += e * bf2f((unsigned short)v[1]);
        a2 += e * bf2f((unsigned short)v[2]);
        a3 += e * bf2f((unsigned short)v[3]);
      }
      float inv = 1.0f / esum;
      f32x4 bg = ((const f32x4*)b_gat)[lane];
      s16x4 o;
      o[0] = (short)f2bf(tanhf(a0 * inv + bg[0]));
      o[1] = (short)f2bf(tanhf(a1 * inv + bg[1]));
      o[2] = (short)f2bf(tanhf(a2 * inv + bg[2]));
      o[3] = (short)f2bf(tanhf(a3 * inv + bg[3]));
      *(s16x4*)(A2 + (long)d * 512 + lane * 4) = o;
    }
  }
  gbar(bar, 2, nb);

  // ---------------- P4: LSTM gates GEMM + epilogue ----------------
  long sec = (long)N * 256;
  for (int vb = blockIdx.x; vb < 632; vb += nb){
    int bi = vb >> 3, j = vb & 7;
    short* Al = lds;          // 128x64
    short* Bl = lds + 8192;   // 128x64
    int r = lane & 15, g = lane >> 4;
    f32x4 acc[2][8] = {};
    for (int kt = 0; kt < 512; kt += 64){
      #pragma unroll
      for (int jj = 0; jj < 4; jj++){
        int chunk = jj * 256 + wv * 64 + lane;
        int row = chunk >> 3, cc = chunk & 7;
        int ccs = cc ^ (row & 7);
        const short* gpa = A2 + (long)(bi * 128 + row) * 512 + kt + ccs * 8;
        __builtin_amdgcn_global_load_lds((gu32*)gpa, (lu32*)&Al[(jj * 256 + wv * 64) * 8], 16, 0, 0);
        int brow = (row >> 5) * 256 + j * 32 + (row & 31);
        const short* gpb = Wcat + (long)brow * 512 + kt + ccs * 8;
        __builtin_amdgcn_global_load_lds((gu32*)gpb, (lu32*)&Bl[(jj * 256 + wv * 64) * 8], 16, 0, 0);
      }
      __syncthreads();
      #pragma unroll
      for (int kk = 0; kk < 2; kk++){
        int kx = kk * 64 + g * 16;
        int sw = kx ^ ((r & 7) << 4);
        bf16x8 a0 = *(const bf16x8*)((const char*)Al + (wv * 32 + r) * 128 + sw);
        bf16x8 a1 = *(const bf16x8*)((const char*)Al + (wv * 32 + 16 + r) * 128 + sw);
        #pragma unroll
        for (int t = 0; t < 8; t++){
          bf16x8 b = *(const bf16x8*)((const char*)Bl + (t * 16 + r) * 128 + sw);
          acc[0][t] = __builtin_amdgcn_mfma_f32_16x16x32_bf16(a0, b, acc[0][t], 0, 0, 0);
          acc[1][t] = __builtin_amdgcn_mfma_f32_16x16x32_bf16(a1, b, acc[1][t], 0, 0, 0);
        }
      }
      __syncthreads();
    }
    int row0 = bi * 128 + wv * 32;
    #pragma unroll
    for (int m = 0; m < 2; m++){
      #pragma unroll
      for (int q = 0; q < 4; q++){
        int row = row0 + m * 16 + g * 4 + q;
        if (row >= N) continue;
        #pragma unroll
        for (int dc = 0; dc < 2; dc++){
          int dcol = j * 32 + dc * 16 + r;
          float iv = acc[m][dc][q];
          float fv = acc[m][dc + 2][q];
          float gv = acc[m][dc + 4][q];
          float ov = acc[m][dc + 6][q];
          long idx = (long)row * 256 + dcol;
          float c0v = c0[idx];
          float ii = 1.f / (1.f + expf(-iv));
          float ff = 1.f / (1.f + expf(-fv));
          float gg = tanhf(gv);
          float oo = 1.f / (1.f + expf(-ov));
          float c1 = ff * c0v + ii * gg;
          float h1 = oo * tanhf(c1);
          out[idx] = h1;
          out[sec + idx] = h1;
          out[2 * sec + idx] = c1;
        }
      }
    }
  }
}

extern "C" void kernel_launch(void* const* d_in, const int* in_sizes, int n_in,
                              void* d_out, int out_size, void* d_ws, size_t ws_size,
                              hipStream_t stream){
  const float* x     = (const float*)d_in[0];
  const int*   ei    = (const int*)d_in[1];
  const float* h     = (const float*)d_in[2];
  const float* c     = (const float*)d_in[3];
  const float* W_gat = (const float*)d_in[4];
  const float* att_s = (const float*)d_in[5];
  const float* att_d = (const float*)d_in[6];
  const float* b_gat = (const float*)d_in[7];
  const float* W_ih  = (const float*)d_in[8];
  const float* W_hh  = (const float*)d_in[9];
  int N  = in_sizes[0] / DIM;   // 10000
  int E  = in_sizes[1] / 2;     // 320000

  char* ws = (char*)d_ws;
  size_t off = 0;
  auto alloc = [&](size_t bytes) -> void* {
    void* p = ws + off;
    off += (bytes + 255) & ~(size_t)255;
    return p;
  };
  short* xw_bf = (short*)alloc((size_t)MPAD * 256 * 2);
  short* A2    = (short*)alloc((size_t)MPAD * 512 * 2);
  short* x_bf  = (short*)alloc((size_t)MPAD * 256 * 2);
  short* Wcat  = (short*)alloc((size_t)1024 * 512 * 2);
  short* WgT   = (short*)alloc((size_t)256 * 256 * 2);
  float* w_s   = (float*)alloc((size_t)256 * 4);
  float* w_d   = (float*)alloc((size_t)256 * 4);
  float* a_s   = (float*)alloc((size_t)N * 4);
  float* a_d   = (float*)alloc((size_t)N * 4);
  int*   curs  = (int*)alloc((size_t)N * 4);
  int*   csr_s = (int*)alloc((size_t)N * CAP * 4);
  float* csr_e = (float*)alloc((size_t)N * CAP * 4);
  int*   bar   = (int*)alloc((size_t)8 * 4);

  float* out = (float*)d_out;

  hipLaunchKernelGGL(k_pre, dim3(512), dim3(256), 0, stream,
                     W_gat, W_ih, W_hh, att_s, att_d,
                     WgT, Wcat, w_s, w_d, curs, bar, N);
  hipLaunchKernelGGL(k_mega, dim3(NB), dim3(256), 0, stream,
                     x, ei, h, c, b_gat, WgT, Wcat, w_s, w_d,
                     x_bf, A2, xw_bf, a_s, a_d, curs, csr_s, csr_e,
                     bar, out, N, E);
}

// Round 8
// 101.148 us; speedup vs baseline: 5.7282x; 5.7282x over previous
//
#include <hip/hip_runtime.h>

// GeniePathLayer: GATConv(heads=1,self-loops) -> tanh -> 1-step LSTM
// N=10000, E=320000, D=256. f32 I/O, bf16 MFMA internally.
// 5 launches: k_pre (weights, w_s/w_d, zero) -> k_rows (convert + att dots)
// -> k_gx (GEMM tiles | edge chunks) -> k_gather -> k_lstm.

#define DIM 256
#define MPAD 10112  // 79 * 128
#define CAP 96      // CSR row capacity; in-deg ~Poisson(32), P(>=96) negligible

typedef __attribute__((ext_vector_type(8))) short bf16x8;
typedef __attribute__((ext_vector_type(4))) short s16x4;
typedef __attribute__((ext_vector_type(4))) float f32x4;
typedef __attribute__((ext_vector_type(4))) int i32x4;

typedef const __attribute__((address_space(1))) unsigned gu32;
typedef __attribute__((address_space(3))) unsigned lu32;

__device__ inline unsigned short f2bf(float f){
  unsigned u = __builtin_bit_cast(unsigned, f);
  unsigned r = u + 0x7FFFu + ((u >> 16) & 1u);
  return (unsigned short)(r >> 16);
}
__device__ inline float bf2f(unsigned short s){
  unsigned u = ((unsigned)s) << 16;
  return __builtin_bit_cast(float, u);
}

// Weights + attention-vector precompute + zeroing (no input-x dependency):
//  w_s=W_gat@att_src, w_d=W_gat@att_dst; curs=0;
//  WgT[d][k]=bf16(W_gat[k][d]); Wcat[j]=[W_ih[j]|W_hh[j]] bf16.
__global__ __launch_bounds__(256) void k_pre(
    const float* __restrict__ W_gat, const float* __restrict__ W_ih,
    const float* __restrict__ W_hh,  const float* __restrict__ att_s,
    const float* __restrict__ att_d,
    short* __restrict__ WgT, short* __restrict__ Wcat,
    float* __restrict__ w_s, float* __restrict__ w_d,
    int* __restrict__ curs, int N){
  long z1 = 512, z2 = N / 4, z3 = 16384, z4 = 131072;
  long total = z1 + z2 + z3 + z4;
  for (long i = blockIdx.x * 256L + threadIdx.x; i < total; i += (long)gridDim.x * 256){
    long p = i;
    if (p < z1){
      int k = (int)(p & 255);
      const float* av = (p < 256) ? att_s : att_d;
      const float* row = W_gat + (long)k * 256;
      float acc = 0.f;
      for (int dd = 0; dd < 256; dd += 4){
        f32x4 wv = *(const f32x4*)(row + dd);
        f32x4 a4 = *(const f32x4*)(av + dd);
        acc += wv[0]*a4[0] + wv[1]*a4[1] + wv[2]*a4[2] + wv[3]*a4[3];
      }
      if (p < 256) w_s[k] = acc; else w_d[k] = acc;
      continue;
    }
    p -= z1;
    if (p < z2){ ((i32x4*)curs)[p] = (i32x4){}; continue; }
    p -= z2;
    if (p < z3){
      long i0 = p * 4;
      int d = (int)(i0 >> 8), k = (int)(i0 & 255);
      s16x4 o;
      #pragma unroll
      for (int j = 0; j < 4; j++) o[j] = (short)f2bf(W_gat[(k + j) * 256 + d]);
      *(s16x4*)(WgT + i0) = o;
      continue;
    }
    p -= z3;
    {
      long i0 = p * 4;
      int jr = (int)(i0 >> 9), k = (int)(i0 & 511);
      f32x4 v = (k < 256) ? *(const f32x4*)(W_ih + (long)jr * 256 + k)
                          : *(const f32x4*)(W_hh + (long)jr * 256 + (k - 256));
      s16x4 o;
      #pragma unroll
      for (int j = 0; j < 4; j++) o[j] = (short)f2bf(v[j]);
      *(s16x4*)(Wcat + i0) = o;
    }
  }
}

// Per-row: x->bf16, a_s[n]=x[n].w_s, a_d[n]=x[n].w_d, h->A2 right half;
// pad rows (N..MPAD) zeroed. One wave per row, grid = MPAD/4 blocks.
__global__ __launch_bounds__(256) void k_rows(
    const float* __restrict__ x, const float* __restrict__ h,
    const float* __restrict__ w_s, const float* __restrict__ w_d,
    short* __restrict__ x_bf, short* __restrict__ A2,
    float* __restrict__ a_s, float* __restrict__ a_d, int N){
  int wv = threadIdx.x >> 6, lane = threadIdx.x & 63;
  int n = blockIdx.x * 4 + wv;
  if (n >= MPAD) return;
  if (n < N){
    f32x4 xv = *(const f32x4*)(x + (long)n * 256 + lane * 4);
    s16x4 ox;
    #pragma unroll
    for (int j = 0; j < 4; j++) ox[j] = (short)f2bf(xv[j]);
    *(s16x4*)(x_bf + (long)n * 256 + lane * 4) = ox;
    f32x4 ws4 = ((const f32x4*)w_s)[lane];
    f32x4 wd4 = ((const f32x4*)w_d)[lane];
    float ps = xv[0]*ws4[0] + xv[1]*ws4[1] + xv[2]*ws4[2] + xv[3]*ws4[3];
    float pd = xv[0]*wd4[0] + xv[1]*wd4[1] + xv[2]*wd4[2] + xv[3]*wd4[3];
    #pragma unroll
    for (int off = 32; off > 0; off >>= 1){
      ps += __shfl_xor(ps, off);
      pd += __shfl_xor(pd, off);
    }
    if (lane == 0){ a_s[n] = ps; a_d[n] = pd; }
    f32x4 hv = *(const f32x4*)(h + (long)n * 256 + lane * 4);
    s16x4 oh;
    #pragma unroll
    for (int j = 0; j < 4; j++) oh[j] = (short)f2bf(hv[j]);
    *(s16x4*)(A2 + (long)n * 512 + 256 + lane * 4) = oh;
  } else {
    s16x4 z = {};
    *(s16x4*)(x_bf + (long)n * 256 + lane * 4) = z;
    *(s16x4*)(A2 + (long)n * 512 + lane * 4) = z;
    *(s16x4*)(A2 + (long)n * 512 + 256 + lane * 4) = z;
  }
}

// Fused independent grid: blocks [0,316) compute xw_bf = bf16(x@W_gat) tiles
// (m97-style 128x64 LDS staging); blocks [316, 316+nchunks) do the per-edge
// softmax scatter e=exp(leaky(a_s[src]+a_d[dst])) into the fixed-CAP CSR.
__global__ __launch_bounds__(256) void k_gx(
    const short* __restrict__ xbf, const short* __restrict__ wT,
    const int* __restrict__ ei, const float* __restrict__ a_s,
    const float* __restrict__ a_d,
    short* __restrict__ xw_bf, int* curs,
    int* __restrict__ csr_s, float* __restrict__ csr_e, int E, int N){
  __shared__ short Al[128 * 64];
  __shared__ short Bl[64 * 64];
  int tid = threadIdx.x;
  if (blockIdx.x < 316){
    int bi = blockIdx.x % 79, bj = blockIdx.x / 79;
    int wv = tid >> 6, lane = tid & 63;
    int r = lane & 15, g = lane >> 4;
    f32x4 acc[2][4] = {};
    for (int kt = 0; kt < 256; kt += 64){
      #pragma unroll
      for (int jj = 0; jj < 4; jj++){
        int chunk = jj * 256 + wv * 64 + lane;
        int row = chunk >> 3, cc = chunk & 7;
        int ccs = cc ^ (row & 7);
        const short* gp = xbf + (long)(bi * 128 + row) * 256 + kt + ccs * 8;
        __builtin_amdgcn_global_load_lds((gu32*)gp, (lu32*)&Al[(jj * 256 + wv * 64) * 8], 16, 0, 0);
      }
      #pragma unroll
      for (int jj = 0; jj < 2; jj++){
        int chunk = jj * 256 + wv * 64 + lane;
        int row = chunk >> 3, cc = chunk & 7;
        int ccs = cc ^ (row & 7);
        const short* gp = wT + (long)(bj * 64 + row) * 256 + kt + ccs * 8;
        __builtin_amdgcn_global_load_lds((gu32*)gp, (lu32*)&Bl[(jj * 256 + wv * 64) * 8], 16, 0, 0);
      }
      __syncthreads();
      #pragma unroll
      for (int kk = 0; kk < 2; kk++){
        int kx = kk * 64 + g * 16;
        int sw = kx ^ ((r & 7) << 4);
        bf16x8 a0 = *(const bf16x8*)((const char*)Al + (wv * 32 + r) * 128 + sw);
        bf16x8 a1 = *(const bf16x8*)((const char*)Al + (wv * 32 + 16 + r) * 128 + sw);
        #pragma unroll
        for (int t = 0; t < 4; t++){
          bf16x8 b = *(const bf16x8*)((const char*)Bl + (t * 16 + r) * 128 + sw);
          acc[0][t] = __builtin_amdgcn_mfma_f32_16x16x32_bf16(a0, b, acc[0][t], 0, 0, 0);
          acc[1][t] = __builtin_amdgcn_mfma_f32_16x16x32_bf16(a1, b, acc[1][t], 0, 0, 0);
        }
      }
      __syncthreads();
    }
    int row0 = bi * 128 + wv * 32;
    #pragma unroll
    for (int m = 0; m < 2; m++){
      #pragma unroll
      for (int q = 0; q < 4; q++){
        int row = row0 + m * 16 + g * 4 + q;
        if (row < N){
          #pragma unroll
          for (int t = 0; t < 4; t++){
            xw_bf[(long)row * 256 + bj * 64 + t * 16 + r] = (short)f2bf(acc[m][t][q]);
          }
        }
      }
    }
  } else {
    int t = (blockIdx.x - 316) * 256 + tid;
    if (t < E + N){
      int s = (t < E) ? ei[t] : (t - E);
      int d = (t < E) ? ei[E + t] : (t - E);
      float al = a_s[s] + a_d[d];
      al = (al > 0.f) ? al : 0.2f * al;
      float e = expf(al);
      int pos = atomicAdd(curs + d, 1);
      if (pos < CAP){
        csr_s[d * CAP + pos] = s;
        csr_e[d * CAP + pos] = e;
      }
    }
  }
}

// per dst row: softmax-weighted gather of bf16 xw rows; denom in-loop;
// xb = tanh(acc/esum + b_gat) -> bf16 into A2 left half. 8-way ILP.
__global__ __launch_bounds__(256) void k_gather(
    const int* __restrict__ curs, const int* __restrict__ csr_s,
    const float* __restrict__ csr_e, const short* __restrict__ xwb,
    const float* __restrict__ b_gat, short* __restrict__ A2, int N){
  int d = blockIdx.x * 4 + (threadIdx.x >> 6);
  if (d >= N) return;
  int lane = threadIdx.x & 63;
  int cnt = curs[d];
  if (cnt > CAP) cnt = CAP;
  int s0 = d * CAP, s1 = s0 + cnt;
  float esum = 0.f;
  float a0 = 0.f, a1 = 0.f, a2 = 0.f, a3 = 0.f;
  int k = s0;
  for (; k + 7 < s1; k += 8){
    int ss[8]; float ee[8]; s16x4 vvv[8];
    #pragma unroll
    for (int u = 0; u < 8; u++){ ss[u] = csr_s[k + u]; ee[u] = csr_e[k + u]; }
    #pragma unroll
    for (int u = 0; u < 8; u++)
      vvv[u] = *(const s16x4*)(xwb + (long)ss[u] * 256 + lane * 4);
    #pragma unroll
    for (int u = 0; u < 8; u++){
      esum += ee[u];
      a0 += ee[u] * bf2f((unsigned short)vvv[u][0]);
      a1 += ee[u] * bf2f((unsigned short)vvv[u][1]);
      a2 += ee[u] * bf2f((unsigned short)vvv[u][2]);
      a3 += ee[u] * bf2f((unsigned short)vvv[u][3]);
    }
  }
  for (; k < s1; k++){
    int s = csr_s[k];
    float e = csr_e[k];
    s16x4 v = *(const s16x4*)(xwb + (long)s * 256 + lane * 4);
    esum += e;
    a0 += e * bf2f((unsigned short)v[0]);
    a1 += e * bf2f((unsigned short)v[1]);
    a2 += e * bf2f((unsigned short)v[2]);
    a3 += e * bf2f((unsigned short)v[3]);
  }
  float inv = 1.0f / esum;
  f32x4 bg = ((const f32x4*)b_gat)[lane];
  s16x4 o;
  o[0] = (short)f2bf(tanhf(a0 * inv + bg[0]));
  o[1] = (short)f2bf(tanhf(a1 * inv + bg[1]));
  o[2] = (short)f2bf(tanhf(a2 * inv + bg[2]));
  o[3] = (short)f2bf(tanhf(a3 * inv + bg[3]));
  *(s16x4*)(A2 + (long)d * 512 + lane * 4) = o;
}

// gates = [xb|h] @ Wcat^T with LDS staging + fused LSTM epilogue.
// Grid (79, 8); block col j covers gate-relative cols [j*32, j*32+32) of all
// 4 gates (B tile rows gate-interleaved) so the epilogue is thread-local.
__global__ __launch_bounds__(256) void k_lstm(
    const short* __restrict__ A2, const short* __restrict__ Wcat,
    const float* __restrict__ c0, float* __restrict__ out, int N){
  __shared__ short Al[128 * 64];
  __shared__ short Bl[128 * 64];
  int w = threadIdx.x >> 6, lane = threadIdx.x & 63;
  int bi = blockIdx.x, j = blockIdx.y;
  int r = lane & 15, g = lane >> 4;
  f32x4 acc[2][8] = {};
  for (int kt = 0; kt < 512; kt += 64){
    #pragma unroll
    for (int jj = 0; jj < 4; jj++){
      int chunk = jj * 256 + w * 64 + lane;
      int row = chunk >> 3, cc = chunk & 7;
      int ccs = cc ^ (row & 7);
      const short* gpa = A2 + (long)(bi * 128 + row) * 512 + kt + ccs * 8;
      __builtin_amdgcn_global_load_lds((gu32*)gpa, (lu32*)&Al[(jj * 256 + w * 64) * 8], 16, 0, 0);
      int brow = (row >> 5) * 256 + j * 32 + (row & 31);
      const short* gpb = Wcat + (long)brow * 512 + kt + ccs * 8;
      __builtin_amdgcn_global_load_lds((gu32*)gpb, (lu32*)&Bl[(jj * 256 + w * 64) * 8], 16, 0, 0);
    }
    __syncthreads();
    #pragma unroll
    for (int kk = 0; kk < 2; kk++){
      int kx = kk * 64 + g * 16;
      int sw = kx ^ ((r & 7) << 4);
      bf16x8 a0 = *(const bf16x8*)((const char*)Al + (w * 32 + r) * 128 + sw);
      bf16x8 a1 = *(const bf16x8*)((const char*)Al + (w * 32 + 16 + r) * 128 + sw);
      #pragma unroll
      for (int t = 0; t < 8; t++){
        bf16x8 b = *(const bf16x8*)((const char*)Bl + (t * 16 + r) * 128 + sw);
        acc[0][t] = __builtin_amdgcn_mfma_f32_16x16x32_bf16(a0, b, acc[0][t], 0, 0, 0);
        acc[1][t] = __builtin_amdgcn_mfma_f32_16x16x32_bf16(a1, b, acc[1][t], 0, 0, 0);
      }
    }
    __syncthreads();
  }
  long sec = (long)N * 256;
  int row0 = bi * 128 + w * 32;
  #pragma unroll
  for (int m = 0; m < 2; m++){
    #pragma unroll
    for (int q = 0; q < 4; q++){
      int row = row0 + m * 16 + g * 4 + q;
      if (row >= N) continue;
      #pragma unroll
      for (int dc = 0; dc < 2; dc++){
        int dcol = j * 32 + dc * 16 + r;
        float iv = acc[m][dc][q];
        float fv = acc[m][dc + 2][q];
        float gv = acc[m][dc + 4][q];
        float ov = acc[m][dc + 6][q];
        long idx = (long)row * 256 + dcol;
        float c0v = c0[idx];
        float ii = 1.f / (1.f + expf(-iv));
        float ff = 1.f / (1.f + expf(-fv));
        float gg = tanhf(gv);
        float oo = 1.f / (1.f + expf(-ov));
        float c1 = ff * c0v + ii * gg;
        float h1 = oo * tanhf(c1);
        out[idx] = h1;
        out[sec + idx] = h1;
        out[2 * sec + idx] = c1;
      }
    }
  }
}

extern "C" void kernel_launch(void* const* d_in, const int* in_sizes, int n_in,
                              void* d_out, int out_size, void* d_ws, size_t ws_size,
                              hipStream_t stream){
  const float* x     = (const float*)d_in[0];
  const int*   ei    = (const int*)d_in[1];
  const float* h     = (const float*)d_in[2];
  const float* c     = (const float*)d_in[3];
  const float* W_gat = (const float*)d_in[4];
  const float* att_s = (const float*)d_in[5];
  const float* att_d = (const float*)d_in[6];
  const float* b_gat = (const float*)d_in[7];
  const float* W_ih  = (const float*)d_in[8];
  const float* W_hh  = (const float*)d_in[9];
  int N  = in_sizes[0] / DIM;   // 10000
  int E  = in_sizes[1] / 2;     // 320000

  char* ws = (char*)d_ws;
  size_t off = 0;
  auto alloc = [&](size_t bytes) -> void* {
    void* p = ws + off;
    off += (bytes + 255) & ~(size_t)255;
    return p;
  };
  short* xw_bf = (short*)alloc((size_t)MPAD * 256 * 2);
  short* A2    = (short*)alloc((size_t)MPAD * 512 * 2);
  short* x_bf  = (short*)alloc((size_t)MPAD * 256 * 2);
  short* Wcat  = (short*)alloc((size_t)1024 * 512 * 2);
  short* WgT   = (short*)alloc((size_t)256 * 256 * 2);
  float* w_s   = (float*)alloc((size_t)256 * 4);
  float* w_d   = (float*)alloc((size_t)256 * 4);
  float* a_s   = (float*)alloc((size_t)N * 4);
  float* a_d   = (float*)alloc((size_t)N * 4);
  int*   curs  = (int*)alloc((size_t)N * 4);
  int*   csr_s = (int*)alloc((size_t)N * CAP * 4);
  float* csr_e = (float*)alloc((size_t)N * CAP * 4);

  float* out = (float*)d_out;

  int nchunks = (E + N + 255) / 256;  // 1290
  hipLaunchKernelGGL(k_pre, dim3(512), dim3(256), 0, stream,
                     W_gat, W_ih, W_hh, att_s, att_d,
                     WgT, Wcat, w_s, w_d, curs, N);
  hipLaunchKernelGGL(k_rows, dim3(MPAD / 4), dim3(256), 0, stream,
                     x, h, w_s, w_d, x_bf, A2, a_s, a_d, N);
  hipLaunchKernelGGL(k_gx, dim3(316 + nchunks), dim3(256), 0, stream,
                     x_bf, WgT, ei, a_s, a_d, xw_bf, curs, csr_s, csr_e, E, N);
  hipLaunchKernelGGL(k_gather, dim3(N / 4), dim3(256), 0, stream,
                     curs, csr_s, csr_e, xw_bf, b_gat, A2, N);
  hipLaunchKernelGGL(k_lstm, dim3(MPAD / 128, 8), dim3(256), 0, stream,
                     A2, Wcat, c, out, N);
}